// Round 8
// baseline (97.031 us; speedup 1.0000x reference)
//
#include <hip/hip_runtime.h>
#include <hip/hip_bf16.h>

// Problem constants
#define D_DIM 512
#define K_DIM 512
#define B_C   64

// Tile config: 128x128 tile, 4 waves (2x2), BK=32, 2-deep prefetch, 3 blocks/CU
#define BM 128
#define BN 128
#define BK 32
#define KSTEPS 16            // D_DIM / BK
#define ROWT 8               // LMAX / BM
#define COLT 4               // K_DIM / BN
#define NWG  (B_C * ROWT * COLT)   // 2048, divisible by 8 XCDs

typedef __attribute__((ext_vector_type(8))) short bf16x8;
typedef __attribute__((ext_vector_type(4))) short bf16x4;
typedef __attribute__((ext_vector_type(4))) float f32x4;
typedef __attribute__((ext_vector_type(2))) float f32x2;

__device__ __forceinline__ short f2bf(float f) {
    union { __hip_bfloat16 h; short s; } u;
    u.h = __float2bfloat16(f);
    return u.s;
}

// Rows are 64 B (32 bf16) = 4 x 16B slots. Swizzle: slot' = slot ^ ((row>>1)&3).
// Derived conflict-free (at volume floor) for A-writes (b64) and frag reads (b128);
// B-writes are 2x of an 8-cy floor (negligible).
__device__ __forceinline__ char* lds_addr(short* base, int row, int slot, int byte_in_slot) {
    return (char*)base + row * 64 + ((slot ^ ((row >> 1) & 3)) << 4) + byte_in_slot;
}

__global__ __launch_bounds__(256, 3) void jbmm_kernel(
    const int* __restrict__ offsets,   // B+1
    const int* __restrict__ index,     // B
    const float* __restrict__ jagged,  // T x D
    const float* __restrict__ weight,  // NW x D x K
    const float* __restrict__ bias,    // NW x K
    float* __restrict__ out)           // T x K
{
    // 32 KiB total: allows LDS-side 5 blocks/CU; VGPR gives 3
    __shared__ short As[2][BM * BK];   // 8 KB per buffer
    __shared__ short Bs[2][BN * BK];   // 8 KB per buffer

    // XCD chunk swizzle (2048 % 8 == 0 -> bijective)
    const int bidRaw = blockIdx.x;
    const int bid = (bidRaw & 7) * (NWG / 8) + (bidRaw >> 3);

    const int b   = bid / (ROWT * COLT);
    const int rt  = (bid / COLT) % ROWT;
    const int ct  = bid % COLT;

    const int start = offsets[b];
    const int end   = offsets[b + 1];
    const int m0    = start + rt * BM;
    if (m0 >= end) return;
    const int rows = (end - m0) < BM ? (end - m0) : BM;

    const int idxw = index[b];
    const float* W = weight + (size_t)idxw * D_DIM * K_DIM;
    const int n0 = ct * BN;

    const int tid  = threadIdx.x;
    const int lane = tid & 63;
    const int wid  = tid >> 6;
    const int wr   = wid >> 1;   // wave row (2x2)
    const int wc   = wid & 1;    // wave col
    const int lr   = lane & 15;
    const int lg   = lane >> 4;

    // staging maps
    const int arow = tid >> 3;   // 0..31 (+32*i): A row
    const int aq   = tid & 7;    // col-quad within 32-f32 row chunk
    const int wnp  = tid & 63;   // B n-pair: rows 2*wnp, 2*wnp+1
    const int wko  = tid >> 6;   // B k-octet 0..3

    float bias_v[4];
#pragma unroll
    for (int ni = 0; ni < 4; ++ni)
        bias_v[ni] = bias[(size_t)idxw * K_DIM + n0 + wc * 64 + ni * 16 + lr];

    f32x4 acc[4][4];
#pragma unroll
    for (int mi = 0; mi < 4; ++mi)
#pragma unroll
        for (int ni = 0; ni < 4; ++ni)
            acc[mi][ni] = (f32x4){0.f, 0.f, 0.f, 0.f};

    // 2-deep prefetch register sets
    f32x4 aR[2][4];   // A: 4 rows x 16B
    f32x2 bR[2][8];   // B: 8 k-rows x 8B (2 n)

#define LOADA(k0_, s_)                                                      \
    {                                                                       \
        _Pragma("unroll")                                                   \
        for (int i = 0; i < 4; ++i) {                                       \
            const int r = arow + 32 * i;                                    \
            f32x4 v = (f32x4){0.f, 0.f, 0.f, 0.f};                          \
            if (r < rows)                                                   \
                v = *reinterpret_cast<const f32x4*>(                        \
                    &jagged[(size_t)(m0 + r) * D_DIM + (k0_) + aq * 4]);    \
            aR[s_][i] = v;                                                  \
        }                                                                   \
    }

#define LOADB(k0_, s_)                                                      \
    {                                                                       \
        _Pragma("unroll")                                                   \
        for (int jj = 0; jj < 8; ++jj)                                      \
            bR[s_][jj] = *reinterpret_cast<const f32x2*>(                   \
                &W[(size_t)((k0_) + wko * 8 + jj) * K_DIM + n0 + wnp * 2]); \
    }

#define CVTSTORE(s_, c_)                                                    \
    {                                                                       \
        _Pragma("unroll")                                                   \
        for (int i = 0; i < 4; ++i) {                                       \
            const int r = arow + 32 * i;                                    \
            bf16x4 w4;                                                      \
            w4[0] = f2bf(aR[s_][i][0]); w4[1] = f2bf(aR[s_][i][1]);         \
            w4[2] = f2bf(aR[s_][i][2]); w4[3] = f2bf(aR[s_][i][3]);         \
            *reinterpret_cast<bf16x4*>(                                     \
                lds_addr(&As[c_][0], r, aq >> 1, (aq & 1) * 8)) = w4;       \
        }                                                                   \
        _Pragma("unroll")                                                   \
        for (int j = 0; j < 2; ++j) {                                       \
            const int rb = wnp * 2 + j;                                     \
            bf16x8 w8;                                                      \
            w8[0] = f2bf(bR[s_][0][j]); w8[1] = f2bf(bR[s_][1][j]);         \
            w8[2] = f2bf(bR[s_][2][j]); w8[3] = f2bf(bR[s_][3][j]);         \
            w8[4] = f2bf(bR[s_][4][j]); w8[5] = f2bf(bR[s_][5][j]);         \
            w8[6] = f2bf(bR[s_][6][j]); w8[7] = f2bf(bR[s_][7][j]);         \
            *reinterpret_cast<bf16x8*>(                                     \
                lds_addr(&Bs[c_][0], rb, wko, 0)) = w8;                     \
        }                                                                   \
    }

#define COMPUTE(c_)                                                         \
    {                                                                       \
        __builtin_amdgcn_s_setprio(1);                                      \
        bf16x8 af[4], bfr[4];                                               \
        _Pragma("unroll")                                                   \
        for (int mi = 0; mi < 4; ++mi)                                      \
            af[mi] = *reinterpret_cast<bf16x8*>(                            \
                lds_addr(&As[c_][0], wr * 64 + mi * 16 + lr, lg, 0));       \
        _Pragma("unroll")                                                   \
        for (int ni = 0; ni < 4; ++ni)                                      \
            bfr[ni] = *reinterpret_cast<bf16x8*>(                           \
                lds_addr(&Bs[c_][0], wc * 64 + ni * 16 + lr, lg, 0));       \
        _Pragma("unroll")                                                   \
        for (int mi = 0; mi < 4; ++mi)                                      \
            _Pragma("unroll")                                               \
            for (int ni = 0; ni < 4; ++ni)                                  \
                acc[mi][ni] = __builtin_amdgcn_mfma_f32_16x16x32_bf16(      \
                    af[mi], bfr[ni], acc[mi][ni], 0, 0, 0);                 \
        __builtin_amdgcn_s_setprio(0);                                      \
    }

// Raw barrier: only LDS ops must be complete; global loads stay in flight.
#define BARRIER_LDS()                                                       \
    {                                                                       \
        asm volatile("s_waitcnt lgkmcnt(0)" ::: "memory");                  \
        __builtin_amdgcn_s_barrier();                                       \
        asm volatile("" ::: "memory");                                      \
    }

    // ---- prologue: tiles 0 and 1 issued; tile 0 staged ----
    LOADA(0, 0); LOADB(0, 0);
    LOADA(BK, 1); LOADB(BK, 1);
    CVTSTORE(0, 0);
    BARRIER_LDS();

    // ---- main loop: tile t+2 issued at step t -> ~1.5 intervals coverage ----
#pragma unroll
    for (int t = 0; t < KSTEPS; ++t) {
        if (t + 2 < KSTEPS) {
            const int kn = (t + 2) * BK;
            LOADA(kn, t & 1); LOADB(kn, t & 1);    // set (t+2)&1 == t&1
        }
        COMPUTE(t & 1);
        if (t + 1 < KSTEPS) {
            CVTSTORE((t + 1) & 1, (t + 1) & 1);    // waits only its own (older) loads
            BARRIER_LDS();
        }
    }

    // ---- epilogue: C/D layout col=lane&15, row=(lane>>4)*4+r ----
#pragma unroll
    for (int mi = 0; mi < 4; ++mi) {
        const int rloc = wr * 64 + mi * 16 + lg * 4;
#pragma unroll
        for (int r = 0; r < 4; ++r) {
            const int rr = rloc + r;
            if (rr < rows) {
#pragma unroll
                for (int ni = 0; ni < 4; ++ni) {
                    out[(size_t)(m0 + rr) * K_DIM + n0 + wc * 64 + ni * 16 + lr] =
                        acc[mi][ni][r] + bias_v[ni];
                }
            }
        }
    }
}

extern "C" void kernel_launch(void* const* d_in, const int* in_sizes, int n_in,
                              void* d_out, int out_size, void* d_ws, size_t ws_size,
                              hipStream_t stream) {
    const int*   offsets = (const int*)d_in[1];
    const int*   index   = (const int*)d_in[2];
    const float* jagged  = (const float*)d_in[3];
    const float* weight  = (const float*)d_in[4];
    const float* bias    = (const float*)d_in[5];
    float*       out     = (float*)d_out;

    dim3 grid(NWG);
    dim3 block(256);
    hipLaunchKernelGGL(jbmm_kernel, grid, block, 0, stream,
                       offsets, index, jagged, weight, bias, out);
}

// Round 9
// 56.807 us; speedup vs baseline: 1.7081x; 1.7081x over previous
//
#include <hip/hip_runtime.h>
#include <hip/hip_bf16.h>

// Problem constants
#define D_DIM 512
#define K_DIM 512
#define B_C   64

// Tile config: 128x128 tile, 4 waves (2x2), BK=32, 16 hand-unrolled steps,
// 3-set (2-step-deep) A prefetch, 1-set B prefetch, LDS double-buffer 32 KiB.
#define BM 128
#define BN 128
#define BK 32
#define KSTEPS 16            // D_DIM / BK
#define ROWT 8               // LMAX / BM
#define COLT 4               // K_DIM / BN
#define NWG  (B_C * ROWT * COLT)   // 2048, divisible by 8 XCDs

typedef __attribute__((ext_vector_type(8))) short bf16x8;
typedef __attribute__((ext_vector_type(4))) short bf16x4;
typedef __attribute__((ext_vector_type(4))) float f32x4;
typedef __attribute__((ext_vector_type(2))) float f32x2;

__device__ __forceinline__ short f2bf(float f) {
    union { __hip_bfloat16 h; short s; } u;
    u.h = __float2bfloat16(f);
    return u.s;
}

// Rows are 64 B (32 bf16) = 4 x 16B slots. Swizzle: slot' = slot ^ ((row>>1)&3).
// A-writes (b64, full-row coverage) and frag reads (b128, 16-row x 4-slot) are
// at the bank floor; B-writes are 2x floor (accepted).
__device__ __forceinline__ char* lds_addr(short* base, int row, int slot, int byteoff) {
    return (char*)base + row * 64 + (((slot ^ ((row >> 1) & 3))) << 4) + byteoff;
}

__global__ __launch_bounds__(256) void jbmm_kernel(
    const int* __restrict__ offsets,   // B+1
    const int* __restrict__ index,     // B
    const float* __restrict__ jagged,  // T x D
    const float* __restrict__ weight,  // NW x D x K
    const float* __restrict__ bias,    // NW x K
    float* __restrict__ out)           // T x K
{
    __shared__ short As[2][BM * BK];   // 8 KB each
    __shared__ short Bs[2][BN * BK];   // 8 KB each

    // XCD chunk swizzle (2048 % 8 == 0 -> bijective)
    const int bidRaw = blockIdx.x;
    const int bid = (bidRaw & 7) * (NWG / 8) + (bidRaw >> 3);

    const int b   = bid / (ROWT * COLT);
    const int rt  = (bid / COLT) % ROWT;
    const int ct  = bid % COLT;

    const int start = offsets[b];
    const int end   = offsets[b + 1];
    const int m0    = start + rt * BM;
    if (m0 >= end) return;
    const int rows = (end - m0) < BM ? (end - m0) : BM;

    const int idxw = index[b];
    const float* W = weight + (size_t)idxw * D_DIM * K_DIM;
    const int n0 = ct * BN;

    const int tid  = threadIdx.x;
    const int lane = tid & 63;
    const int wid  = tid >> 6;
    const int wr   = wid >> 1;   // wave row (2x2)
    const int wc   = wid & 1;    // wave col
    const int lr   = lane & 15;
    const int lg   = lane >> 4;

    // staging maps
    const int arow = tid >> 3;   // 0..31 (+32*i): A row
    const int aq   = tid & 7;    // 0..7: 4 consecutive f32 at k = aq*4
    const int wnp  = tid & 63;   // B n-pair: rows 2*wnp, 2*wnp+1
    const int wko  = tid >> 6;   // B k-octet 0..3

    float bias_v[4];
#pragma unroll
    for (int ni = 0; ni < 4; ++ni)
        bias_v[ni] = bias[(size_t)idxw * K_DIM + n0 + wc * 64 + ni * 16 + lr];

    f32x4 acc[4][4];
#pragma unroll
    for (int mi = 0; mi < 4; ++mi)
#pragma unroll
        for (int ni = 0; ni < 4; ++ni)
            acc[mi][ni] = (f32x4){0.f, 0.f, 0.f, 0.f};

    // 3 named A prefetch sets (NO runtime indexing) + 1 B set
    f32x4 aR0[4], aR1[4], aR2[4];
    f32x2 bR[8];

#define LOADA(k0_, SET_)                                                    \
    {                                                                       \
        _Pragma("unroll")                                                   \
        for (int i = 0; i < 4; ++i) {                                       \
            const int r = arow + 32 * i;                                    \
            f32x4 v = (f32x4){0.f, 0.f, 0.f, 0.f};                          \
            if (r < rows)                                                   \
                v = *reinterpret_cast<const f32x4*>(                        \
                    &jagged[(size_t)(m0 + r) * D_DIM + (k0_) + aq * 4]);    \
            SET_[i] = v;                                                    \
        }                                                                   \
    }

#define LOADB(k0_)                                                          \
    {                                                                       \
        _Pragma("unroll")                                                   \
        for (int jj = 0; jj < 8; ++jj)                                      \
            bR[jj] = *reinterpret_cast<const f32x2*>(                       \
                &W[(size_t)((k0_) + wko * 8 + jj) * K_DIM + n0 + wnp * 2]); \
    }

#define CVTSTORE(SET_, c_)                                                  \
    {                                                                       \
        _Pragma("unroll")                                                   \
        for (int i = 0; i < 4; ++i) {                                       \
            const int r = arow + 32 * i;                                    \
            bf16x4 w4;                                                      \
            w4[0] = f2bf(SET_[i][0]); w4[1] = f2bf(SET_[i][1]);             \
            w4[2] = f2bf(SET_[i][2]); w4[3] = f2bf(SET_[i][3]);             \
            *reinterpret_cast<bf16x4*>(                                     \
                lds_addr(&As[c_][0], r, aq >> 1, (aq & 1) * 8)) = w4;       \
        }                                                                   \
        _Pragma("unroll")                                                   \
        for (int j = 0; j < 2; ++j) {                                       \
            const int rb = wnp * 2 + j;                                     \
            bf16x8 w8;                                                      \
            w8[0] = f2bf(bR[0][j]); w8[1] = f2bf(bR[1][j]);                 \
            w8[2] = f2bf(bR[2][j]); w8[3] = f2bf(bR[3][j]);                 \
            w8[4] = f2bf(bR[4][j]); w8[5] = f2bf(bR[5][j]);                 \
            w8[6] = f2bf(bR[6][j]); w8[7] = f2bf(bR[7][j]);                 \
            *reinterpret_cast<bf16x8*>(                                     \
                lds_addr(&Bs[c_][0], rb, wko, 0)) = w8;                     \
        }                                                                   \
    }

#define COMPUTE(c_)                                                         \
    {                                                                       \
        __builtin_amdgcn_s_setprio(1);                                      \
        bf16x8 af[4], bfr[4];                                               \
        _Pragma("unroll")                                                   \
        for (int mi = 0; mi < 4; ++mi)                                      \
            af[mi] = *reinterpret_cast<bf16x8*>(                            \
                lds_addr(&As[c_][0], wr * 64 + mi * 16 + lr, lg, 0));       \
        _Pragma("unroll")                                                   \
        for (int ni = 0; ni < 4; ++ni)                                      \
            bfr[ni] = *reinterpret_cast<bf16x8*>(                           \
                lds_addr(&Bs[c_][0], wc * 64 + ni * 16 + lr, lg, 0));       \
        _Pragma("unroll")                                                   \
        for (int mi = 0; mi < 4; ++mi)                                      \
            _Pragma("unroll")                                               \
            for (int ni = 0; ni < 4; ++ni)                                  \
                acc[mi][ni] = __builtin_amdgcn_mfma_f32_16x16x32_bf16(      \
                    af[mi], bfr[ni], acc[mi][ni], 0, 0, 0);                 \
        __builtin_amdgcn_s_setprio(0);                                      \
    }

// Raw barrier: only LDS ops must drain; global loads stay in flight.
#define BARRIER_LDS()                                                       \
    {                                                                       \
        asm volatile("s_waitcnt lgkmcnt(0)" ::: "memory");                  \
        __builtin_amdgcn_s_barrier();                                       \
        asm volatile("" ::: "memory");                                      \
    }

// Step T (all constants): issue A tile T+2 into AL_, B tile T+1; compute buf
// T&1; stage tile T+1 (A from AC_, loaded at step T-1 -> ~2 steps coverage).
#define STEP(T_, AL_, AC_)                                                  \
    {                                                                       \
        if ((T_) + 2 < KSTEPS) LOADA(((T_) + 2) * BK, AL_);                 \
        if ((T_) + 1 < KSTEPS) LOADB(((T_) + 1) * BK);                      \
        COMPUTE((T_) & 1);                                                  \
        if ((T_) + 1 < KSTEPS) {                                            \
            CVTSTORE(AC_, ((T_) + 1) & 1);                                  \
            BARRIER_LDS();                                                  \
        }                                                                   \
    }

    // ---- prologue ----
    LOADA(0, aR0);
    LOADA(BK, aR1);
    LOADB(0);
    CVTSTORE(aR0, 0);
    BARRIER_LDS();

    // ---- 16 hand-unrolled steps; A-set pattern period 3 ----
    STEP(0,  aR2, aR1)
    STEP(1,  aR0, aR2)
    STEP(2,  aR1, aR0)
    STEP(3,  aR2, aR1)
    STEP(4,  aR0, aR2)
    STEP(5,  aR1, aR0)
    STEP(6,  aR2, aR1)
    STEP(7,  aR0, aR2)
    STEP(8,  aR1, aR0)
    STEP(9,  aR2, aR1)
    STEP(10, aR0, aR2)
    STEP(11, aR1, aR0)
    STEP(12, aR2, aR1)
    STEP(13, aR0, aR2)
    STEP(14, aR1, aR0)
    STEP(15, aR2, aR1)

    // ---- epilogue: C/D layout col=lane&15, row=(lane>>4)*4+r ----
#pragma unroll
    for (int mi = 0; mi < 4; ++mi) {
        const int rloc = wr * 64 + mi * 16 + lg * 4;
#pragma unroll
        for (int r = 0; r < 4; ++r) {
            const int rr = rloc + r;
            if (rr < rows) {
#pragma unroll
                for (int ni = 0; ni < 4; ++ni) {
                    out[(size_t)(m0 + rr) * K_DIM + n0 + wc * 64 + ni * 16 + lr] =
                        acc[mi][ni][r] + bias_v[ni];
                }
            }
        }
    }
}

extern "C" void kernel_launch(void* const* d_in, const int* in_sizes, int n_in,
                              void* d_out, int out_size, void* d_ws, size_t ws_size,
                              hipStream_t stream) {
    const int*   offsets = (const int*)d_in[1];
    const int*   index   = (const int*)d_in[2];
    const float* jagged  = (const float*)d_in[3];
    const float* weight  = (const float*)d_in[4];
    const float* bias    = (const float*)d_in[5];
    float*       out     = (float*)d_out;

    dim3 grid(NWG);
    dim3 block(256);
    hipLaunchKernelGGL(jbmm_kernel, grid, block, 0, stream,
                       offsets, index, jagged, weight, bias, out);
}